// Round 1
// baseline (33.200 us; speedup 1.0000x reference)
//
#include <hip/hip_runtime.h>

// Problem constants (from setup_inputs: B=128, H=W=384)
#define ROWS 128
#define NCOL 147456              // 384*384
#define BPR  16                  // blocks per row in the reduction
#define TPB  256
#define CHUNK (NCOL / BPR)       // 9216 floats per block
#define N4    (CHUNK / 4)        // 2304 float4 per block
static constexpr long long K0 = 117964;  // int((1.0 - 0.2) * NCOL)

// ---------------- Pass 1: per-(row,chunk) partial {sum(res), count(valid)} --
__global__ __launch_bounds__(TPB) void reduce_kernel(
    const float* __restrict__ pred, const float* __restrict__ tgt,
    float* __restrict__ psum, unsigned* __restrict__ pcnt) {
  const int row = blockIdx.x / BPR;
  const int blk = blockIdx.x % BPR;
  const size_t base = (size_t)row * NCOL + (size_t)blk * CHUNK;
  const float4* __restrict__ p4 = (const float4*)(pred + base);
  const float4* __restrict__ t4 = (const float4*)(tgt + base);

  float s = 0.f;
  unsigned c = 0;
  for (int i = threadIdx.x; i < N4; i += TPB) {   // exactly 9 iters/thread
    float4 p = p4[i];
    float4 t = t4[i];
    {
      bool v = t.x > 0.f; float r = v ? fabsf(p.x - t.x) : 0.f; s += r; c += v;
    }
    {
      bool v = t.y > 0.f; float r = v ? fabsf(p.y - t.y) : 0.f; s += r; c += v;
    }
    {
      bool v = t.z > 0.f; float r = v ? fabsf(p.z - t.z) : 0.f; s += r; c += v;
    }
    {
      bool v = t.w > 0.f; float r = v ? fabsf(p.w - t.w) : 0.f; s += r; c += v;
    }
  }

  // wave64 shuffle reduce, then 4 waves via LDS
  for (int off = 32; off > 0; off >>= 1) {
    s += __shfl_down(s, off, 64);
    c += __shfl_down(c, off, 64);
  }
  __shared__ float ss[4];
  __shared__ unsigned sc[4];
  const int wave = threadIdx.x >> 6, lane = threadIdx.x & 63;
  if (lane == 0) { ss[wave] = s; sc[wave] = c; }
  __syncthreads();
  if (threadIdx.x == 0) {
    for (int i = 1; i < 4; ++i) { s += ss[i]; c += sc[i]; }
    psum[blockIdx.x] = s;
    pcnt[blockIdx.x] = c;
  }
}

// ---------------- Pass 2: per-row stats, clip check ------------------------
__global__ void rowstat_kernel(const float* __restrict__ psum,
                               const unsigned* __restrict__ pcnt,
                               float* __restrict__ row_loss,
                               long long* __restrict__ row_k,
                               int* __restrict__ row_flag) {
  const int row = threadIdx.x;  // one block of ROWS threads
  float s = 0.f;
  unsigned c = 0;
  for (int i = 0; i < BPR; ++i) {
    s += psum[row * BPR + i];
    c += pcnt[row * BPR + i];
  }
  const long long k = (long long)(NCOL - (long long)c) + K0;  // max_index pre-clip
  if (k >= (long long)(NCOL - 1)) {
    // threshold = max residual -> nothing trimmed (res > thresh never true)
    row_flag[row] = 0;
    row_k[row] = 0;
    row_loss[row] = (c > 0) ? s / (2.0f * (float)c) : 0.f;
  } else {
    // general case: need exact k-th order statistic (handled by select_kernel)
    row_flag[row] = 1;
    row_k[row] = k;
    row_loss[row] = 0.f;
  }
}

// ---------------- Pass 3 (rare): radix-select threshold + trimmed sum ------
// res >= 0, so float bit pattern order == value order.
__global__ __launch_bounds__(256) void select_kernel(
    const float* __restrict__ pred, const float* __restrict__ tgt,
    const int* __restrict__ row_flag, const long long* __restrict__ row_k,
    float* __restrict__ row_loss) {
  const int row = blockIdx.x;
  if (row_flag[row] == 0) return;  // hot path: all rows exit here

  const float* __restrict__ p = pred + (size_t)row * NCOL;
  const float* __restrict__ t = tgt + (size_t)row * NCOL;

  __shared__ unsigned hist[256];
  __shared__ unsigned sh_sel;
  __shared__ long long sh_kk;

  unsigned prefix = 0, prefmask = 0;
  long long kk = row_k[row];

  for (int shift = 24; shift >= 0; shift -= 8) {
    hist[threadIdx.x] = 0;  // 256 threads == 256 bins
    __syncthreads();
    for (int i = threadIdx.x; i < NCOL; i += 256) {
      const float ti = t[i];
      const float r = (ti > 0.f) ? fabsf(p[i] - ti) : 0.f;
      const unsigned u = __float_as_uint(r);
      if ((u & prefmask) == prefix) atomicAdd(&hist[(u >> shift) & 255u], 1u);
    }
    __syncthreads();
    if (threadIdx.x == 0) {
      long long cum = 0;
      unsigned sel = 255;
      for (int b = 0; b < 256; ++b) {
        const long long h = (long long)hist[b];
        if (kk < cum + h) { sel = (unsigned)b; break; }
        cum += h;
      }
      sh_sel = sel;
      sh_kk = kk - cum;
    }
    __syncthreads();
    prefix |= (sh_sel << shift);
    prefmask |= (255u << shift);
    kk = sh_kk;
    __syncthreads();
  }

  const float thresh = __uint_as_float(prefix);

  // trimmed sum: keep res <= thresh (duplicates of thresh are all kept)
  float s = 0.f;
  unsigned c = 0;
  for (int i = threadIdx.x; i < NCOL; i += 256) {
    const float ti = t[i];
    const bool v = ti > 0.f;
    const float r = v ? fabsf(p[i] - ti) : 0.f;
    if (r <= thresh) s += r;
    c += v;
  }
  for (int off = 32; off > 0; off >>= 1) {
    s += __shfl_down(s, off, 64);
    c += __shfl_down(c, off, 64);
  }
  __shared__ float ss[4];
  __shared__ unsigned sc[4];
  const int wave = threadIdx.x >> 6, lane = threadIdx.x & 63;
  if (lane == 0) { ss[wave] = s; sc[wave] = c; }
  __syncthreads();
  if (threadIdx.x == 0) {
    for (int i = 1; i < 4; ++i) { s += ss[i]; c += sc[i]; }
    row_loss[row] = (c > 0) ? s / (2.0f * (float)c) : 0.f;
  }
}

// ---------------- Pass 4: mean over rows -----------------------------------
__global__ void final_kernel(const float* __restrict__ row_loss,
                             float* __restrict__ out) {
  float v = row_loss[threadIdx.x];  // ROWS=128 threads
  for (int off = 32; off > 0; off >>= 1) v += __shfl_down(v, off, 64);
  __shared__ float sh[2];
  const int wave = threadIdx.x >> 6, lane = threadIdx.x & 63;
  if (lane == 0) sh[wave] = v;
  __syncthreads();
  if (threadIdx.x == 0) out[0] = (sh[0] + sh[1]) / (float)ROWS;
}

extern "C" void kernel_launch(void* const* d_in, const int* in_sizes, int n_in,
                              void* d_out, int out_size, void* d_ws, size_t ws_size,
                              hipStream_t stream) {
  const float* pred = (const float*)d_in[0];
  const float* tgt  = (const float*)d_in[1];
  float* out = (float*)d_out;

  char* ws = (char*)d_ws;
  float* psum        = (float*)ws;     ws += (size_t)ROWS * BPR * sizeof(float);
  unsigned* pcnt     = (unsigned*)ws;  ws += (size_t)ROWS * BPR * sizeof(unsigned);
  float* row_loss    = (float*)ws;     ws += (size_t)ROWS * sizeof(float);
  long long* row_k   = (long long*)ws; ws += (size_t)ROWS * sizeof(long long);
  int* row_flag      = (int*)ws;       ws += (size_t)ROWS * sizeof(int);

  reduce_kernel<<<ROWS * BPR, TPB, 0, stream>>>(pred, tgt, psum, pcnt);
  rowstat_kernel<<<1, ROWS, 0, stream>>>(psum, pcnt, row_loss, row_k, row_flag);
  select_kernel<<<ROWS, 256, 0, stream>>>(pred, tgt, row_flag, row_k, row_loss);
  final_kernel<<<1, ROWS, 0, stream>>>(row_loss, out);
}